// Round 6
// baseline (1080.327 us; speedup 1.0000x reference)
//
#include <hip/hip_runtime.h>
#include <math.h>

// Problem constants (DirectImageAlign): B=4, C=16, H=240, W=320
#define B_   4
#define C_   16
#define H_   240
#define W_   320
#define HW_  (H_*W_)
#define TPB  256
#define NBLK (HW_/TPB)     // 300 blocks per batch
#define NACC 27            // 21 (sym 6x6 JtJ) + 6 (rhs)
#define GEOM_W_ 0.01f
#define HUBER_  1.345f
#define LM_EPS_ 1e-6
#define N_ITERS_ 5
#define NXCD 8

typedef float f4u __attribute__((ext_vector_type(4), aligned(4)));
typedef float f2u __attribute__((ext_vector_type(2), aligned(4)));

// init: copy pose into d_out, zero the per-iteration accumulators + tickets
__global__ void dia_init(const float* __restrict__ pose_in, float* __restrict__ pose,
                         double* __restrict__ acc, int* __restrict__ tick) {
    const int i = threadIdx.x;
    if (i < N_ITERS_ * B_ * NACC) acc[i] = 0.0;
    if (i < N_ITERS_ * B_) tick[i] = 0;
    if (i < B_ * 16) pose[i] = pose_in[i];
}

// Scalar-gather bilinear sample + central-diff gradients (boundary fallback).
__device__ __forceinline__ void samp12s(const float* __restrict__ base,
                                        int x0, int xm1, int xp2,
                                        int ro0, int rum, int rdp,
                                        float w00, float w10, float w01, float w11,
                                        float& sv, float& sdx, float& sdy)
{
    const float* r0 = base + ro0;
    const float* r1 = r0 + W_;
    float A0 = r0[xm1], A1 = r0[x0], A2 = r0[x0+1], A3 = r0[xp2];
    float B0 = r1[xm1], B1 = r1[x0], B2 = r1[x0+1], B3 = r1[xp2];
    f2u uv = *(const f2u*)(base + rum + x0);
    f2u dv = *(const f2u*)(base + rdp + x0);
    sv  = w00*A1 + w10*A2 + w01*B1 + w11*B2;
    sdx = 0.5f*( w00*(A2-A0) + w10*(A3-A1) + w01*(B2-B0) + w11*(B3-B1) );
    sdy = 0.5f*( w00*(B1-uv[0]) + w10*(B2-uv[1]) + w01*(dv[0]-A1) + w11*(dv[1]-A2) );
}

// 6x6 LM solve + se3_exp + pose compose, one thread. Cold path.
__device__ __attribute__((noinline)) void solve_update(const double* __restrict__ S,
                                                       float* __restrict__ P)
{
    double Hm[6][7];
    {
        int k = 0;
        double JtJ[6][6];
        for (int i = 0; i < 6; ++i)
            for (int j = i; j < 6; ++j) { JtJ[i][j] = S[k]; JtJ[j][i] = S[k]; ++k; }
        for (int i = 0; i < 6; ++i) {
            for (int j = 0; j < 6; ++j) Hm[i][j] = JtJ[i][j] + (i == j ? LM_EPS_ : 0.0);
            Hm[i][6] = S[21 + i];
        }
    }
    double xi[6];
    for (int col = 0; col < 6; ++col) {
        int piv = col; double mx = fabs(Hm[col][col]);
        for (int r2 = col+1; r2 < 6; ++r2) { double a = fabs(Hm[r2][col]); if (a > mx) { mx = a; piv = r2; } }
        if (piv != col)
            for (int j2 = col; j2 < 7; ++j2) { double tmp = Hm[col][j2]; Hm[col][j2] = Hm[piv][j2]; Hm[piv][j2] = tmp; }
        const double inv = 1.0 / Hm[col][col];
        for (int r2 = col+1; r2 < 6; ++r2) {
            const double f = Hm[r2][col] * inv;
            for (int j2 = col; j2 < 7; ++j2) Hm[r2][j2] -= f * Hm[col][j2];
        }
    }
    for (int r2 = 5; r2 >= 0; --r2) {
        double s = Hm[r2][6];
        for (int j2 = r2+1; j2 < 6; ++j2) s -= Hm[r2][j2] * xi[j2];
        xi[r2] = s / Hm[r2][r2];
    }

    const double vx = xi[0], vy = xi[1], vz = xi[2];
    const double wx = xi[3], wy = xi[4], wz = xi[5];
    const double t2 = wx*wx + wy*wy + wz*wz;
    double A, Bc, Cc;
    if (t2 < 1e-8) {
        A  = 1.0 - t2 / 6.0;
        Bc = 0.5 - t2 / 24.0;
        Cc = 1.0/6.0 - t2 / 120.0;
    } else {
        const double th = sqrt(t2);
        const double sth = sin(th), cth = cos(th);
        A  = sth / th;
        Bc = (1.0 - cth) / t2;
        Cc = (th - sth) / (t2 * th);
    }
    const double Wm[9] = { 0.0, -wz,  wy,
                           wz,  0.0, -wx,
                          -wy,  wx,  0.0 };
    double W2[9];
    for (int i = 0; i < 3; ++i)
        for (int j = 0; j < 3; ++j) {
            double s = 0.0;
            for (int k = 0; k < 3; ++k) s += Wm[i*3+k] * Wm[k*3+j];
            W2[i*3+j] = s;
        }
    double Rm[9], Vm[9];
    for (int i = 0; i < 9; ++i) {
        const double id = (i % 4 == 0) ? 1.0 : 0.0;
        Rm[i] = id + A  * Wm[i] + Bc * W2[i];
        Vm[i] = id + Bc * Wm[i] + Cc * W2[i];
    }
    const double tx = Vm[0]*vx + Vm[1]*vy + Vm[2]*vz;
    const double ty = Vm[3]*vx + Vm[4]*vy + Vm[5]*vz;
    const double tz = Vm[6]*vx + Vm[7]*vy + Vm[8]*vz;

    double Pm[16];
    for (int i = 0; i < 16; ++i) Pm[i] = (double)P[i];
    double E[16] = { Rm[0], Rm[1], Rm[2], tx,
                     Rm[3], Rm[4], Rm[5], ty,
                     Rm[6], Rm[7], Rm[8], tz,
                     0.0,   0.0,   0.0,   1.0 };
    double out[16];
    for (int i = 0; i < 4; ++i)
        for (int j = 0; j < 4; ++j) {
            double s = 0.0;
            for (int k = 0; k < 4; ++k) s += E[i*4+k] * Pm[k*4+j];
            out[i*4+j] = s;
        }
    for (int i = 0; i < 16; ++i) P[i] = (float)out[i];
}

// Per-channel Gram update from named patch registers
#define GRAM_CH(Aq, Cq, Uq, Dq, sq)                                            \
    {                                                                          \
        const float Iw  = w00*Aq[1] + w10*Aq[2] + w01*Cq[1] + w11*Cq[2];       \
        const float gxc = 0.5f*( w00*(Aq[2]-Aq[0]) + w10*(Aq[3]-Aq[1])         \
                               + w01*(Cq[2]-Cq[0]) + w11*(Cq[3]-Cq[1]) );      \
        const float gyc = 0.5f*( w00*(Cq[1]-Uq[0]) + w10*(Cq[2]-Uq[1])         \
                               + w01*(Dq[0]-Aq[1]) + w11*(Dq[1]-Aq[2]) );      \
        const float r  = sq - Iw;                                              \
        const float ar = fabsf(r);                                             \
        const float wc = (ar <= HUBER_) ? 1.f : HUBER_ / fmaxf(ar, 1e-8f);     \
        Ga  += wc * gxc * gxc;                                                 \
        Gb  += wc * gxc * gyc;                                                 \
        Gd  += wc * gyc * gyc;                                                 \
        grx += wc * r * gxc;                                                   \
        gry += wc * r * gyc;                                                   \
    }

__global__ __launch_bounds__(256, 4) void dia_reduce(
    float* __restrict__ pose,
    const float* __restrict__ I0,
    const float* __restrict__ I1,
    const float* __restrict__ intr,
    const float* __restrict__ depth0,
    const float* __restrict__ depth1,
    double* __restrict__ acc,     // [B_][NACC] for this iteration
    int* __restrict__ tick)       // [B_] ticket for this iteration
{
    // XCD-chunked bijective swizzle (1200 % 8 == 0): consecutive image strips
    // land on the same XCD's L2 (they share 3 of 4 patch rows x 16 channels).
    const int bid = blockIdx.x;
    const int swz = (bid & (NXCD-1)) * (NBLK * B_ / NXCD) + (bid >> 3);
    const int b     = swz / NBLK;
    const int strip = swz - b * NBLK;
    const int p = strip * TPB + threadIdx.x;          // HW_ == NBLK*TPB exactly

    const float fxv = intr[b*4+0], fyv = intr[b*4+1];
    const float cx  = intr[b*4+2], cy  = intr[b*4+3];
    const float ifx = 1.0f / fxv,  ify = 1.0f / fyv;

    float Rm[9], tv[3];
#pragma unroll
    for (int i = 0; i < 3; ++i) {
#pragma unroll
        for (int j = 0; j < 3; ++j) Rm[i*3+j] = pose[b*16 + i*4 + j];
        tv[i] = pose[b*16 + i*4 + 3];
    }

    const float* d0p = depth0 + b * HW_;
    const float* d1p = depth1 + b * HW_;
    const float* I0b = I0 + (size_t)b * C_ * HW_;
    const float* I1b = I1 + (size_t)b * C_ * HW_;

    float Jw0[6] = {0,0,0,0,0,0};
    float Jw1[6] = {0,0,0,0,0,0};
    float JZ[6]  = {0,0,0,0,0,0};
    float Ga = 0.f, Gb = 0.f, Gd = 0.f, grx = 0.f, gry = 0.f, wz2 = 0.f, rZ = 0.f;

    {
        const int v = p / W_;
        const int u = p - v * W_;

        const float d1 = d1p[p];
        const float d0 = d0p[p];
        const float X1x = d1 * ((float)u - cx) * ifx;
        const float X1y = d1 * ((float)v - cy) * ify;
        const float x = Rm[0]*X1x + Rm[1]*X1y + Rm[2]*d1 + tv[0];
        const float y = Rm[3]*X1x + Rm[4]*X1y + Rm[5]*d1 + tv[1];
        const float z = Rm[6]*X1x + Rm[7]*X1y + Rm[8]*d1 + tv[2];

        const bool vproj = z > 1e-6f;
        const float zs = vproj ? z : 1.0f;
        const float iz = 1.0f / zs;
        const float u0 = fxv * x * iz + cx;
        const float v0 = fyv * y * iz + cy;
        const bool inb = (u0 > 0.f) && (u0 < (float)(W_-1)) && (v0 > 0.f) && (v0 < (float)(H_-1));
        const bool valid = inb && vproj && (d0 > 0.f) && (d1 > 0.f);

        if (valid) {
            const float x0f = floorf(u0), y0f = floorf(v0);
            const int x0 = (int)x0f, y0 = (int)y0f;
            const float fx1 = u0 - x0f, fy1 = v0 - y0f;
            const float w00 = (1.f-fx1)*(1.f-fy1), w10 = fx1*(1.f-fy1);
            const float w01 = (1.f-fx1)*fy1,       w11 = fx1*fy1;
            const int xm1 = max(x0-1, 0), xp2 = min(x0+2, W_-1);
            const int ym1 = max(y0-1, 0), yp2 = min(y0+2, H_-1);
            const bool interior = (x0 >= 1) && (x0 <= W_-3);
            const int ro0 = y0 * W_;
            const int rum = ym1 * W_;
            const int rdp = yp2 * W_;

            // Warp Jacobian Jw = Jp(2x3) @ Jt(3x6)
            {
                const float a0 = fxv * iz;
                const float a2 = -fxv * x * iz * iz;
                const float b1 = fyv * iz;
                const float b2 = -fyv * y * iz * iz;
                Jw0[0] = a0;           Jw0[1] = 0.f;   Jw0[2] = a2;
                Jw0[3] = a2 * y;       Jw0[4] = a0*z - a2*x; Jw0[5] = -a0*y;
                Jw1[0] = 0.f;          Jw1[1] = b1;    Jw1[2] = b2;
                Jw1[3] = -b1*z + b2*y; Jw1[4] = -b2*x; Jw1[5] = b1*x;
            }

            // Geometric residual (depth patch)
            {
                float D0w, dDx, dDy;
                samp12s(d0p, x0, xm1, xp2, ro0, rum, rdp,
                        w00, w10, w01, w11, D0w, dDx, dDy);
                rZ = z - D0w;
#pragma unroll
                for (int j = 0; j < 6; ++j) JZ[j] = dDx*Jw0[j] + dDy*Jw1[j];
                JZ[2] -= 1.f; JZ[3] -= y; JZ[4] += x;
                const float arz = fabsf(GEOM_W_ * rZ);
                const float wzw = (arz <= HUBER_) ? 1.f : HUBER_ / fmaxf(arz, 1e-8f);
                wz2 = wzw * GEOM_W_ * GEOM_W_;
            }

            // 16 photometric channels -> 2x2 Gram + 2-vector.
            // Interior fast path: 4 channels per batch, ALL 20 loads issued
            // into NAMED registers (no arrays -> no scratch) before any math.
            if (interior) {
                const float* bp0 = I0b + ro0 + x0 - 1;       // row y0, x0-1
                const float* bp1 = bp0 + W_;                 // row y0+1
                const float* bpu = I0b + rum + x0;           // row ym1
                const float* bpd = I0b + rdp + x0;           // row yp2
                const float* i1p = I1b + p;
                for (int cc = 0; cc < C_; cc += 4) {
                    const size_t o0 = (size_t)cc * HW_;
                    const size_t o1 = o0 + HW_;
                    const size_t o2 = o1 + HW_;
                    const size_t o3 = o2 + HW_;
                    const f4u A0 = *(const f4u*)(bp0 + o0);
                    const f4u A1 = *(const f4u*)(bp0 + o1);
                    const f4u A2 = *(const f4u*)(bp0 + o2);
                    const f4u A3 = *(const f4u*)(bp0 + o3);
                    const f4u C0 = *(const f4u*)(bp1 + o0);
                    const f4u C1 = *(const f4u*)(bp1 + o1);
                    const f4u C2 = *(const f4u*)(bp1 + o2);
                    const f4u C3 = *(const f4u*)(bp1 + o3);
                    const f2u U0 = *(const f2u*)(bpu + o0);
                    const f2u U1 = *(const f2u*)(bpu + o1);
                    const f2u U2 = *(const f2u*)(bpu + o2);
                    const f2u U3 = *(const f2u*)(bpu + o3);
                    const f2u D0 = *(const f2u*)(bpd + o0);
                    const f2u D1 = *(const f2u*)(bpd + o1);
                    const f2u D2 = *(const f2u*)(bpd + o2);
                    const f2u D3 = *(const f2u*)(bpd + o3);
                    const float s0 = i1p[o0];
                    const float s1 = i1p[o1];
                    const float s2 = i1p[o2];
                    const float s3 = i1p[o3];
                    GRAM_CH(A0, C0, U0, D0, s0)
                    GRAM_CH(A1, C1, U1, D1, s1)
                    GRAM_CH(A2, C2, U2, D2, s2)
                    GRAM_CH(A3, C3, U3, D3, s3)
                }
            } else {
                for (int c = 0; c < C_; ++c) {
                    float Iw, gxc, gyc;
                    samp12s(I0b + (size_t)c * HW_, x0, xm1, xp2, ro0, rum, rdp,
                            w00, w10, w01, w11, Iw, gxc, gyc);
                    const float r = I1b[(size_t)c * HW_ + p] - Iw;
                    const float ar = fabsf(r);
                    const float wc = (ar <= HUBER_) ? 1.f : HUBER_ / fmaxf(ar, 1e-8f);
                    Ga  += wc * gxc * gxc;
                    Gb  += wc * gxc * gyc;
                    Gd  += wc * gyc * gyc;
                    grx += wc * r * gxc;
                    gry += wc * r * gyc;
                }
            }
        }
    }

    // 27 wave shuffle-reductions (values computed on the fly), cross-wave LDS,
    // one f64 device atomic per value per block.
    __shared__ float sred[4][NACC];
    const int lane = threadIdx.x & 63;
    const int wid  = threadIdx.x >> 6;
    int k = 0;
#pragma unroll
    for (int i = 0; i < 6; ++i) {
#pragma unroll
        for (int j = i; j < 6; ++j) {
            float vt = Ga * Jw0[i] * Jw0[j]
                     + Gb * (Jw0[i] * Jw1[j] + Jw1[i] * Jw0[j])
                     + Gd * Jw1[i] * Jw1[j]
                     + wz2 * JZ[i] * JZ[j];
#pragma unroll
            for (int off = 32; off > 0; off >>= 1) vt += __shfl_down(vt, off, 64);
            if (lane == 0) sred[wid][k] = vt;
            ++k;
        }
    }
#pragma unroll
    for (int i = 0; i < 6; ++i) {
        float vt = grx * Jw0[i] + gry * Jw1[i] + wz2 * rZ * JZ[i];
#pragma unroll
        for (int off = 32; off > 0; off >>= 1) vt += __shfl_down(vt, off, 64);
        if (lane == 0) sred[wid][21 + i] = vt;
    }
    __syncthreads();
    if (threadIdx.x < NACC) {
        const double s = (double)sred[0][threadIdx.x] + (double)sred[1][threadIdx.x]
                       + (double)sred[2][threadIdx.x] + (double)sred[3][threadIdx.x];
        atomicAdd(&acc[b * NACC + threadIdx.x], s);
    }
    __syncthreads();

    // Last block of this batch performs the solve + pose update in-kernel.
    if (threadIdx.x == 0) {
        __threadfence();
        const int old = atomicAdd(&tick[b], 1);
        if (old == NBLK - 1) {
            __threadfence();
            double S[NACC];
            for (int i = 0; i < NACC; ++i)
                S[i] = atomicAdd(&acc[b * NACC + i], 0.0);  // coherent read
            solve_update(S, pose + b * 16);
        }
    }
}

extern "C" void kernel_launch(void* const* d_in, const int* in_sizes, int n_in,
                              void* d_out, int out_size, void* d_ws, size_t ws_size,
                              hipStream_t stream) {
    const float* pose_in = (const float*)d_in[0];
    const float* I0      = (const float*)d_in[1];
    const float* I1      = (const float*)d_in[2];
    // d_in[3] = invD0, d_in[4] = invD1 : unused by the forward pass
    const float* intr    = (const float*)d_in[5];
    const float* depth0  = (const float*)d_in[6];
    const float* depth1  = (const float*)d_in[7];

    float*  pose = (float*)d_out;                        // working pose
    double* acc  = (double*)d_ws;                        // 5*4*27 doubles
    int*    tick = (int*)(acc + N_ITERS_ * B_ * NACC);   // 5*4 ints

    hipLaunchKernelGGL(dia_init, dim3(1), dim3(576), 0, stream, pose_in, pose, acc, tick);
    for (int it = 0; it < N_ITERS_; ++it) {
        hipLaunchKernelGGL(dia_reduce, dim3(NBLK * B_), dim3(TPB), 0, stream,
                           pose, I0, I1, intr, depth0, depth1,
                           acc + (size_t)it * B_ * NACC, tick + (size_t)it * B_);
    }
}

// Round 8
// 395.714 us; speedup vs baseline: 2.7301x; 2.7301x over previous
//
#include <hip/hip_runtime.h>
#include <math.h>

// Problem constants (DirectImageAlign): B=4, C=16, H=240, W=320
#define B_   4
#define C_   16
#define H_   240
#define W_   320
#define HW_  (H_*W_)
#define TPB  256
#define TLX  16            // tile width
#define TLY  16            // tile height
#define NTX  (W_/TLX)      // 20 tile columns
#define NTY  (H_/TLY)      // 15 tile rows
#define NTPB (NTX*NTY)     // 300 tiles per batch
#define NACC 27            // 21 (sym 6x6 JtJ) + 6 (rhs)
#define GEOM_W_ 0.01f
#define HUBER_  1.345f
#define LM_EPS_ 1e-6
#define N_ITERS_ 5
#define NXCD 8

typedef float f4u __attribute__((ext_vector_type(4), aligned(4)));
typedef float f2u __attribute__((ext_vector_type(2), aligned(4)));

// init: copy pose into d_out, zero the per-iteration accumulators + tickets
__global__ void dia_init(const float* __restrict__ pose_in, float* __restrict__ pose,
                         double* __restrict__ acc, int* __restrict__ tick) {
    const int i = threadIdx.x;
    if (i < N_ITERS_ * B_ * NACC) acc[i] = 0.0;
    if (i < N_ITERS_ * B_) tick[i] = 0;
    if (i < B_ * 16) pose[i] = pose_in[i];
}

// Bilinear sample of img, d/dx, d/dy at (x0+fx1, y0+fy1); central-difference
// gradients with edge clamping. Vectorized row loads for interior pixels.
// Proven no-spill structure (R4: 48 VGPR, WRITE_SIZE 0.34 MB).
__device__ __forceinline__ void samp12v(const float* __restrict__ base,
                                        int x0, bool interior, int xm1, int xp2,
                                        int ro0, int rum, int rdp,
                                        float w00, float w10, float w01, float w11,
                                        float& sv, float& sdx, float& sdy)
{
    const float* r0 = base + ro0;
    const float* r1 = r0 + W_;
    float A0, A1, A2, A3, B0, B1, B2, B3;
    if (interior) {
        f4u a = *(const f4u*)(r0 + x0 - 1);
        f4u c = *(const f4u*)(r1 + x0 - 1);
        A0 = a[0]; A1 = a[1]; A2 = a[2]; A3 = a[3];
        B0 = c[0]; B1 = c[1]; B2 = c[2]; B3 = c[3];
    } else {
        A0 = r0[xm1]; A1 = r0[x0]; A2 = r0[x0+1]; A3 = r0[xp2];
        B0 = r1[xm1]; B1 = r1[x0]; B2 = r1[x0+1]; B3 = r1[xp2];
    }
    f2u uv = *(const f2u*)(base + rum + x0);
    f2u dv = *(const f2u*)(base + rdp + x0);
    sv  = w00*A1 + w10*A2 + w01*B1 + w11*B2;
    sdx = 0.5f*( w00*(A2-A0) + w10*(A3-A1) + w01*(B2-B0) + w11*(B3-B1) );
    sdy = 0.5f*( w00*(B1-uv[0]) + w10*(B2-uv[1]) + w01*(dv[0]-A1) + w11*(dv[1]-A2) );
}

// 6x6 LM solve + se3_exp + pose compose, one thread. Cold path.
__device__ __attribute__((noinline)) void solve_update(const double* __restrict__ S,
                                                       float* __restrict__ P)
{
    double Hm[6][7];
    {
        int k = 0;
        double JtJ[6][6];
        for (int i = 0; i < 6; ++i)
            for (int j = i; j < 6; ++j) { JtJ[i][j] = S[k]; JtJ[j][i] = S[k]; ++k; }
        for (int i = 0; i < 6; ++i) {
            for (int j = 0; j < 6; ++j) Hm[i][j] = JtJ[i][j] + (i == j ? LM_EPS_ : 0.0);
            Hm[i][6] = S[21 + i];
        }
    }
    double xi[6];
    for (int col = 0; col < 6; ++col) {
        int piv = col; double mx = fabs(Hm[col][col]);
        for (int r2 = col+1; r2 < 6; ++r2) { double a = fabs(Hm[r2][col]); if (a > mx) { mx = a; piv = r2; } }
        if (piv != col)
            for (int j2 = col; j2 < 7; ++j2) { double tmp = Hm[col][j2]; Hm[col][j2] = Hm[piv][j2]; Hm[piv][j2] = tmp; }
        const double inv = 1.0 / Hm[col][col];
        for (int r2 = col+1; r2 < 6; ++r2) {
            const double f = Hm[r2][col] * inv;
            for (int j2 = col; j2 < 7; ++j2) Hm[r2][j2] -= f * Hm[col][j2];
        }
    }
    for (int r2 = 5; r2 >= 0; --r2) {
        double s = Hm[r2][6];
        for (int j2 = r2+1; j2 < 6; ++j2) s -= Hm[r2][j2] * xi[j2];
        xi[r2] = s / Hm[r2][r2];
    }

    const double vx = xi[0], vy = xi[1], vz = xi[2];
    const double wx = xi[3], wy = xi[4], wz = xi[5];
    const double t2 = wx*wx + wy*wy + wz*wz;
    double A, Bc, Cc;
    if (t2 < 1e-8) {
        A  = 1.0 - t2 / 6.0;
        Bc = 0.5 - t2 / 24.0;
        Cc = 1.0/6.0 - t2 / 120.0;
    } else {
        const double th = sqrt(t2);
        const double sth = sin(th), cth = cos(th);
        A  = sth / th;
        Bc = (1.0 - cth) / t2;
        Cc = (th - sth) / (t2 * th);
    }
    const double Wm[9] = { 0.0, -wz,  wy,
                           wz,  0.0, -wx,
                          -wy,  wx,  0.0 };
    double W2[9];
    for (int i = 0; i < 3; ++i)
        for (int j = 0; j < 3; ++j) {
            double s = 0.0;
            for (int k = 0; k < 3; ++k) s += Wm[i*3+k] * Wm[k*3+j];
            W2[i*3+j] = s;
        }
    double Rm[9], Vm[9];
    for (int i = 0; i < 9; ++i) {
        const double id = (i % 4 == 0) ? 1.0 : 0.0;
        Rm[i] = id + A  * Wm[i] + Bc * W2[i];
        Vm[i] = id + Bc * Wm[i] + Cc * W2[i];
    }
    const double tx = Vm[0]*vx + Vm[1]*vy + Vm[2]*vz;
    const double ty = Vm[3]*vx + Vm[4]*vy + Vm[5]*vz;
    const double tz = Vm[6]*vx + Vm[7]*vy + Vm[8]*vz;

    double Pm[16];
    for (int i = 0; i < 16; ++i) Pm[i] = (double)P[i];
    double E[16] = { Rm[0], Rm[1], Rm[2], tx,
                     Rm[3], Rm[4], Rm[5], ty,
                     Rm[6], Rm[7], Rm[8], tz,
                     0.0,   0.0,   0.0,   1.0 };
    double out[16];
    for (int i = 0; i < 4; ++i)
        for (int j = 0; j < 4; ++j) {
            double s = 0.0;
            for (int k = 0; k < 4; ++k) s += E[i*4+k] * Pm[k*4+j];
            out[i*4+j] = s;
        }
    for (int i = 0; i < 16; ++i) P[i] = (float)out[i];
}

__global__ __launch_bounds__(256, 5) void dia_reduce(
    float* __restrict__ pose,
    const float* __restrict__ I0,
    const float* __restrict__ I1,
    const float* __restrict__ intr,
    const float* __restrict__ depth0,
    const float* __restrict__ depth1,
    double* __restrict__ acc,     // [B_][NACC] for this iteration
    int* __restrict__ tick)       // [B_] ticket for this iteration
{
    // 16x16 pixel tiles, column-major tile order within a batch (consecutive
    // indices = vertically adjacent tiles, sharing 3 I0 patch rows x 16 ch).
    // XCD-chunked swizzle: each XCD gets 150 consecutive tiles (10 tile-cols
    // of one batch) -> vertical-neighbor reuse stays in one XCD's L2.
    const int bid = blockIdx.x;                       // 0..1199, 1200 % 8 == 0
    const int swz = (bid & (NXCD-1)) * (NTPB * B_ / NXCD) + (bid >> 3);
    const int b   = swz / NTPB;
    const int tid = swz - b * NTPB;                   // column-major tile id
    const int tlx = tid / NTY;                        // 0..19
    const int tly = tid - tlx * NTY;                  // 0..14
    const int px  = tlx * TLX + (threadIdx.x & (TLX-1));
    const int py  = tly * TLY + (threadIdx.x >> 4);
    const int p   = py * W_ + px;

    const float fxv = intr[b*4+0], fyv = intr[b*4+1];
    const float cx  = intr[b*4+2], cy  = intr[b*4+3];
    const float ifx = 1.0f / fxv,  ify = 1.0f / fyv;

    float Rm[9], tv[3];
#pragma unroll
    for (int i = 0; i < 3; ++i) {
#pragma unroll
        for (int j = 0; j < 3; ++j) Rm[i*3+j] = pose[b*16 + i*4 + j];
        tv[i] = pose[b*16 + i*4 + 3];
    }

    const float* d0p = depth0 + b * HW_;
    const float* d1p = depth1 + b * HW_;
    const float* I0b = I0 + (size_t)b * C_ * HW_;
    const float* I1b = I1 + (size_t)b * C_ * HW_;

    float Jw0[6] = {0,0,0,0,0,0};
    float Jw1[6] = {0,0,0,0,0,0};
    float JZ[6]  = {0,0,0,0,0,0};
    float Ga = 0.f, Gb = 0.f, Gd = 0.f, grx = 0.f, gry = 0.f, wz2 = 0.f, rZ = 0.f;

    {
        const float d1 = d1p[p];
        const float d0 = d0p[p];
        const float X1x = d1 * ((float)px - cx) * ifx;
        const float X1y = d1 * ((float)py - cy) * ify;
        const float x = Rm[0]*X1x + Rm[1]*X1y + Rm[2]*d1 + tv[0];
        const float y = Rm[3]*X1x + Rm[4]*X1y + Rm[5]*d1 + tv[1];
        const float z = Rm[6]*X1x + Rm[7]*X1y + Rm[8]*d1 + tv[2];

        const bool vproj = z > 1e-6f;
        const float zs = vproj ? z : 1.0f;
        const float iz = 1.0f / zs;
        const float u0 = fxv * x * iz + cx;
        const float v0 = fyv * y * iz + cy;
        const bool inb = (u0 > 0.f) && (u0 < (float)(W_-1)) && (v0 > 0.f) && (v0 < (float)(H_-1));
        const bool valid = inb && vproj && (d0 > 0.f) && (d1 > 0.f);

        if (valid) {
            const float x0f = floorf(u0), y0f = floorf(v0);
            const int x0 = (int)x0f, y0 = (int)y0f;
            const float fx1 = u0 - x0f, fy1 = v0 - y0f;
            const float w00 = (1.f-fx1)*(1.f-fy1), w10 = fx1*(1.f-fy1);
            const float w01 = (1.f-fx1)*fy1,       w11 = fx1*fy1;
            const int xm1 = max(x0-1, 0), xp2 = min(x0+2, W_-1);
            const int ym1 = max(y0-1, 0), yp2 = min(y0+2, H_-1);
            const bool interior = (x0 >= 1) && (x0 <= W_-3);
            const int ro0 = y0 * W_;
            const int rum = ym1 * W_;
            const int rdp = yp2 * W_;

            // Warp Jacobian Jw = Jp(2x3) @ Jt(3x6)
            {
                const float a0 = fxv * iz;
                const float a2 = -fxv * x * iz * iz;
                const float b1 = fyv * iz;
                const float b2 = -fyv * y * iz * iz;
                Jw0[0] = a0;           Jw0[1] = 0.f;   Jw0[2] = a2;
                Jw0[3] = a2 * y;       Jw0[4] = a0*z - a2*x; Jw0[5] = -a0*y;
                Jw1[0] = 0.f;          Jw1[1] = b1;    Jw1[2] = b2;
                Jw1[3] = -b1*z + b2*y; Jw1[4] = -b2*x; Jw1[5] = b1*x;
            }

            // Geometric residual (depth patch)
            {
                float D0w, dDx, dDy;
                samp12v(d0p, x0, interior, xm1, xp2, ro0, rum, rdp,
                        w00, w10, w01, w11, D0w, dDx, dDy);
                rZ = z - D0w;
#pragma unroll
                for (int j = 0; j < 6; ++j) JZ[j] = dDx*Jw0[j] + dDy*Jw1[j];
                JZ[2] -= 1.f; JZ[3] -= y; JZ[4] += x;
                const float arz = fabsf(GEOM_W_ * rZ);
                const float wzw = (arz <= HUBER_) ? 1.f : HUBER_ / fmaxf(arz, 1e-8f);
                wz2 = wzw * GEOM_W_ * GEOM_W_;
            }

            // 16 photometric channels -> 2x2 Gram + 2-vector
#pragma unroll 2
            for (int c = 0; c < C_; ++c) {
                float Iw, gxc, gyc;
                samp12v(I0b + (size_t)c * HW_, x0, interior, xm1, xp2, ro0, rum, rdp,
                        w00, w10, w01, w11, Iw, gxc, gyc);
                const float r = I1b[(size_t)c * HW_ + p] - Iw;
                const float ar = fabsf(r);
                const float wc = (ar <= HUBER_) ? 1.f : HUBER_ / fmaxf(ar, 1e-8f);
                Ga  += wc * gxc * gxc;
                Gb  += wc * gxc * gyc;
                Gd  += wc * gyc * gyc;
                grx += wc * r * gxc;
                gry += wc * r * gyc;
            }
        }
    }

    // 27 wave shuffle-reductions (values computed on the fly), cross-wave LDS,
    // one f64 device atomic per value per block.
    __shared__ float sred[4][NACC];
    const int lane = threadIdx.x & 63;
    const int wid  = threadIdx.x >> 6;
    int k = 0;
#pragma unroll
    for (int i = 0; i < 6; ++i) {
#pragma unroll
        for (int j = i; j < 6; ++j) {
            float vt = Ga * Jw0[i] * Jw0[j]
                     + Gb * (Jw0[i] * Jw1[j] + Jw1[i] * Jw0[j])
                     + Gd * Jw1[i] * Jw1[j]
                     + wz2 * JZ[i] * JZ[j];
#pragma unroll
            for (int off = 32; off > 0; off >>= 1) vt += __shfl_down(vt, off, 64);
            if (lane == 0) sred[wid][k] = vt;
            ++k;
        }
    }
#pragma unroll
    for (int i = 0; i < 6; ++i) {
        float vt = grx * Jw0[i] + gry * Jw1[i] + wz2 * rZ * JZ[i];
#pragma unroll
        for (int off = 32; off > 0; off >>= 1) vt += __shfl_down(vt, off, 64);
        if (lane == 0) sred[wid][21 + i] = vt;
    }
    __syncthreads();
    if (threadIdx.x < NACC) {
        const double s = (double)sred[0][threadIdx.x] + (double)sred[1][threadIdx.x]
                       + (double)sred[2][threadIdx.x] + (double)sred[3][threadIdx.x];
        atomicAdd(&acc[b * NACC + threadIdx.x], s);
    }
    __syncthreads();

    // Last block of this batch performs the solve + pose update in-kernel.
    if (threadIdx.x == 0) {
        __threadfence();
        const int old = atomicAdd(&tick[b], 1);
        if (old == NTPB - 1) {
            __threadfence();
            double S[NACC];
            for (int i = 0; i < NACC; ++i)
                S[i] = atomicAdd(&acc[b * NACC + i], 0.0);  // coherent read
            solve_update(S, pose + b * 16);
        }
    }
}

extern "C" void kernel_launch(void* const* d_in, const int* in_sizes, int n_in,
                              void* d_out, int out_size, void* d_ws, size_t ws_size,
                              hipStream_t stream) {
    const float* pose_in = (const float*)d_in[0];
    const float* I0      = (const float*)d_in[1];
    const float* I1      = (const float*)d_in[2];
    // d_in[3] = invD0, d_in[4] = invD1 : unused by the forward pass
    const float* intr    = (const float*)d_in[5];
    const float* depth0  = (const float*)d_in[6];
    const float* depth1  = (const float*)d_in[7];

    float*  pose = (float*)d_out;                        // working pose
    double* acc  = (double*)d_ws;                        // 5*4*27 doubles
    int*    tick = (int*)(acc + N_ITERS_ * B_ * NACC);   // 5*4 ints

    hipLaunchKernelGGL(dia_init, dim3(1), dim3(576), 0, stream, pose_in, pose, acc, tick);
    for (int it = 0; it < N_ITERS_; ++it) {
        hipLaunchKernelGGL(dia_reduce, dim3(NTPB * B_), dim3(TPB), 0, stream,
                           pose, I0, I1, intr, depth0, depth1,
                           acc + (size_t)it * B_ * NACC, tick + (size_t)it * B_);
    }
}